// Round 1
// baseline (399.523 us; speedup 1.0000x reference)
//
#include <hip/hip_runtime.h>

#define HDIM 1024
#define BDIM 32
#define LDIM 1024

// ws layout (floats): u1[0:H], u2[H:2H], vbar[2H : 2H+B*H], logits[2H+B*H : +B*L]

__global__ __launch_bounds__(256) void k_u12(const float* __restrict__ W,
                                             const float* __restrict__ mlp_w,
                                             float* __restrict__ u1,
                                             float* __restrict__ u2) {
    int h  = blockIdx.x * 256 + threadIdx.x;   // blockIdx.x in [0,4)
    int o0 = blockIdx.y * 128;                 // blockIdx.y in [0,8)
    float s1 = 0.f, s2 = 0.f;
    #pragma unroll 8
    for (int o = o0; o < o0 + 128; ++o) {
        float w = W[o * HDIM + h];
        s1 += w * mlp_w[o];
        s2 += w * mlp_w[HDIM + o];
    }
    atomicAdd(&u1[h], s1);
    atomicAdd(&u2[h], s2);
}

__global__ __launch_bounds__(256) void k_logits(const float4* __restrict__ q,
                                                const float4* __restrict__ k,
                                                const float* __restrict__ u1,
                                                const float* __restrict__ u2,
                                                const float* __restrict__ mlp_b,
                                                float* __restrict__ logits) {
    __shared__ float4 su1[256];
    __shared__ float4 su2[256];
    int t = threadIdx.x;
    su1[t] = ((const float4*)u1)[t];
    su2[t] = ((const float4*)u2)[t];
    __syncthreads();
    int wave = t >> 6, lane = t & 63;
    long long row = (long long)blockIdx.x * 4 + wave;   // [0, 32768)
    const float4* qr = q + row * 256;
    const float4* kr = k + row * 256;
    float acc = 0.f;
    #pragma unroll
    for (int i = 0; i < 4; ++i) {
        int idx = lane + 64 * i;
        float4 a  = qr[idx];
        float4 b1 = su1[idx];
        acc += a.x * b1.x + a.y * b1.y + a.z * b1.z + a.w * b1.w;
        float4 c  = kr[idx];
        float4 b2 = su2[idx];
        acc += c.x * b2.x + c.y * b2.y + c.z * b2.z + c.w * b2.w;
    }
    #pragma unroll
    for (int off = 32; off > 0; off >>= 1)
        acc += __shfl_down(acc, off, 64);
    if (lane == 0) {
        float v = acc + mlp_b[0];
        logits[row] = v > 0.f ? v : 0.f;
    }
}

__global__ __launch_bounds__(256) void k_softmax(const float* __restrict__ logits,
                                                 float* __restrict__ score) {
    __shared__ float sm[4];
    __shared__ float ss[4];
    int b = blockIdx.x;
    int t = threadIdx.x;
    int wave = t >> 6, lane = t & 63;
    float4 v = ((const float4*)(logits + b * LDIM))[t];
    float m = fmaxf(fmaxf(v.x, v.y), fmaxf(v.z, v.w));
    #pragma unroll
    for (int off = 32; off > 0; off >>= 1)
        m = fmaxf(m, __shfl_down(m, off, 64));
    if (lane == 0) sm[wave] = m;
    __syncthreads();
    float M = fmaxf(fmaxf(sm[0], sm[1]), fmaxf(sm[2], sm[3]));
    float4 e;
    e.x = __expf(v.x - M); e.y = __expf(v.y - M);
    e.z = __expf(v.z - M); e.w = __expf(v.w - M);
    float s = e.x + e.y + e.z + e.w;
    #pragma unroll
    for (int off = 32; off > 0; off >>= 1)
        s += __shfl_down(s, off, 64);
    if (lane == 0) ss[wave] = s;
    __syncthreads();
    float inv = 1.f / (ss[0] + ss[1] + ss[2] + ss[3]);
    float4 o;
    o.x = e.x * inv; o.y = e.y * inv; o.z = e.z * inv; o.w = e.w * inv;
    ((float4*)(score + b * LDIM))[t] = o;
}

__global__ __launch_bounds__(256) void k_vbar(const float4* __restrict__ value,
                                              const float* __restrict__ score,
                                              float* __restrict__ vbar) {
    int b  = blockIdx.x >> 4;        // [0,32)
    int lc = blockIdx.x & 15;        // 16 l-chunks of 64
    int t  = threadIdx.x;
    const float4* vrow = value + ((long long)b * LDIM + lc * 64) * 256 + t;
    const float*  sc   = score + b * LDIM + lc * 64;
    float4 acc = make_float4(0.f, 0.f, 0.f, 0.f);
    #pragma unroll 8
    for (int l = 0; l < 64; ++l) {
        float s  = sc[l];
        float4 v = vrow[(long long)l * 256];
        acc.x += s * v.x; acc.y += s * v.y; acc.z += s * v.z; acc.w += s * v.w;
    }
    float* dst = vbar + b * HDIM + t * 4;
    atomicAdd(dst + 0, acc.x);
    atomicAdd(dst + 1, acc.y);
    atomicAdd(dst + 2, acc.z);
    atomicAdd(dst + 3, acc.w);
}

__global__ __launch_bounds__(256) void k_result(const float* __restrict__ W,
                                                const float* __restrict__ vbar,
                                                float* __restrict__ result) {
    __shared__ float4 sv[256];
    int b  = blockIdx.x >> 3;        // [0,32)
    int oc = blockIdx.x & 7;         // 8 o-chunks of 128
    int t  = threadIdx.x;
    sv[t] = ((const float4*)(vbar + b * HDIM))[t];
    __syncthreads();
    int wave = t >> 6, lane = t & 63;
    for (int o = oc * 128 + wave; o < oc * 128 + 128; o += 4) {
        const float4* wr = (const float4*)(W + o * HDIM);
        float acc = 0.f;
        #pragma unroll
        for (int i = 0; i < 4; ++i) {
            int idx = lane + 64 * i;
            float4 w = wr[idx];
            float4 v = sv[idx];
            acc += w.x * v.x + w.y * v.y + w.z * v.z + w.w * v.w;
        }
        #pragma unroll
        for (int off = 32; off > 0; off >>= 1)
            acc += __shfl_down(acc, off, 64);
        if (lane == 0) result[b * HDIM + o] = acc;
    }
}

extern "C" void kernel_launch(void* const* d_in, const int* in_sizes, int n_in,
                              void* d_out, int out_size, void* d_ws, size_t ws_size,
                              hipStream_t stream) {
    const float* query = (const float*)d_in[0];
    const float* key   = (const float*)d_in[1];
    const float* value = (const float*)d_in[2];
    const float* W     = (const float*)d_in[3];
    const float* mlp_w = (const float*)d_in[4];
    const float* mlp_b = (const float*)d_in[5];

    float* out    = (float*)d_out;
    float* result = out;                 // B*H = 32768 floats
    float* score  = out + BDIM * LDIM;   // B*L = 32768 floats

    float* u1     = (float*)d_ws;
    float* u2     = u1 + HDIM;
    float* vbar   = u2 + HDIM;           // B*H floats
    float* logits = vbar + BDIM * HDIM;  // B*L floats

    // zero u1, u2, vbar (atomic accumulation targets)
    hipMemsetAsync(d_ws, 0, (size_t)(2 * HDIM + BDIM * HDIM) * sizeof(float), stream);

    k_u12<<<dim3(4, 8), 256, 0, stream>>>(W, mlp_w, u1, u2);
    k_logits<<<(BDIM * LDIM) / 4, 256, 0, stream>>>((const float4*)query, (const float4*)key,
                                                    u1, u2, mlp_b, logits);
    k_softmax<<<BDIM, 256, 0, stream>>>(logits, score);
    k_vbar<<<BDIM * 16, 256, 0, stream>>>((const float4*)value, score, vbar);
    k_result<<<BDIM * 8, 256, 0, stream>>>(W, vbar, result);
}

// Round 2
// 379.250 us; speedup vs baseline: 1.0535x; 1.0535x over previous
//
#include <hip/hip_runtime.h>

#define HDIM 1024
#define BDIM 32
#define LDIM 1024

// ws layout (floats): u1[0:H], u2[H:2H], vbar[2H : 2H+B*H], logits[2H+B*H : +B*L]

// u1[h] = sum_o W[o,h]*w1[o]; u2[h] = sum_o W[o,h]*w2[o]. Coalesced row reads.
__global__ __launch_bounds__(256) void k_u12(const float4* __restrict__ W4,
                                             const float* __restrict__ mlp_w,
                                             float* __restrict__ u1,
                                             float* __restrict__ u2) {
    int t  = threadIdx.x;            // float4 index within a row, [0,256)
    int o0 = blockIdx.x * 16;        // 64 blocks x 16 rows
    float4 s1 = make_float4(0.f, 0.f, 0.f, 0.f);
    float4 s2 = make_float4(0.f, 0.f, 0.f, 0.f);
    #pragma unroll 4
    for (int o = o0; o < o0 + 16; ++o) {
        float4 w = W4[o * 256 + t];
        float c1 = mlp_w[o];
        float c2 = mlp_w[HDIM + o];
        s1.x += w.x * c1; s1.y += w.y * c1; s1.z += w.z * c1; s1.w += w.w * c1;
        s2.x += w.x * c2; s2.y += w.y * c2; s2.z += w.z * c2; s2.w += w.w * c2;
    }
    int h = t * 4;
    atomicAdd(&u1[h + 0], s1.x); atomicAdd(&u1[h + 1], s1.y);
    atomicAdd(&u1[h + 2], s1.z); atomicAdd(&u1[h + 3], s1.w);
    atomicAdd(&u2[h + 0], s2.x); atomicAdd(&u2[h + 1], s2.y);
    atomicAdd(&u2[h + 2], s2.z); atomicAdd(&u2[h + 3], s2.w);
}

// logits[row] = relu(q[row]·u1 + k[row]·u2 + b). u1/u2 fragments in registers.
__global__ __launch_bounds__(256, 4) void k_logits(const float4* __restrict__ q,
                                                   const float4* __restrict__ k,
                                                   const float4* __restrict__ u1v,
                                                   const float4* __restrict__ u2v,
                                                   const float* __restrict__ mlp_b,
                                                   float* __restrict__ logits) {
    int t = threadIdx.x;
    int lane = t & 63, wave = t >> 6;
    float4 a1[4], a2[4];
    #pragma unroll
    for (int i = 0; i < 4; ++i) {
        a1[i] = u1v[lane + 64 * i];
        a2[i] = u2v[lane + 64 * i];
    }
    float bias = mlp_b[0];
    long long wid = (long long)blockIdx.x * 4 + wave;   // [0, 8192)
    #pragma unroll 2
    for (int r = 0; r < 4; ++r) {
        long long row = wid * 4 + r;                    // [0, 32768)
        const float4* qr = q + row * 256;
        const float4* kr = k + row * 256;
        float acc = 0.f;
        #pragma unroll
        for (int i = 0; i < 4; ++i) {
            float4 x = qr[lane + 64 * i];
            acc += x.x * a1[i].x + x.y * a1[i].y + x.z * a1[i].z + x.w * a1[i].w;
            float4 y = kr[lane + 64 * i];
            acc += y.x * a2[i].x + y.y * a2[i].y + y.z * a2[i].z + y.w * a2[i].w;
        }
        #pragma unroll
        for (int off = 32; off > 0; off >>= 1)
            acc += __shfl_down(acc, off, 64);
        if (lane == 0) {
            float v = acc + bias;
            logits[row] = v > 0.f ? v : 0.f;
        }
    }
}

__global__ __launch_bounds__(256) void k_softmax(const float* __restrict__ logits,
                                                 float* __restrict__ score) {
    __shared__ float sm[4];
    __shared__ float ss[4];
    int b = blockIdx.x;
    int t = threadIdx.x;
    int wave = t >> 6, lane = t & 63;
    float4 v = ((const float4*)(logits + b * LDIM))[t];
    float m = fmaxf(fmaxf(v.x, v.y), fmaxf(v.z, v.w));
    #pragma unroll
    for (int off = 32; off > 0; off >>= 1)
        m = fmaxf(m, __shfl_down(m, off, 64));
    if (lane == 0) sm[wave] = m;
    __syncthreads();
    float M = fmaxf(fmaxf(sm[0], sm[1]), fmaxf(sm[2], sm[3]));
    float4 e;
    e.x = __expf(v.x - M); e.y = __expf(v.y - M);
    e.z = __expf(v.z - M); e.w = __expf(v.w - M);
    float s = e.x + e.y + e.z + e.w;
    #pragma unroll
    for (int off = 32; off > 0; off >>= 1)
        s += __shfl_down(s, off, 64);
    if (lane == 0) ss[wave] = s;
    __syncthreads();
    float inv = 1.f / (ss[0] + ss[1] + ss[2] + ss[3]);
    float4 o;
    o.x = e.x * inv; o.y = e.y * inv; o.z = e.z * inv; o.w = e.w * inv;
    ((float4*)(score + b * LDIM))[t] = o;
}

// vbar[b,h] = sum_l score[b,l] * value[b,l,h]
__global__ __launch_bounds__(256, 4) void k_vbar(const float4* __restrict__ value,
                                                 const float* __restrict__ score,
                                                 float* __restrict__ vbar) {
    int b  = blockIdx.x >> 4;        // [0,32)
    int lc = blockIdx.x & 15;        // 16 l-chunks of 64
    int t  = threadIdx.x;
    const float4* vrow = value + ((long long)b * LDIM + lc * 64) * 256 + t;
    const float*  sc   = score + b * LDIM + lc * 64;
    float4 acc0 = make_float4(0.f, 0.f, 0.f, 0.f);
    float4 acc1 = make_float4(0.f, 0.f, 0.f, 0.f);
    #pragma unroll 4
    for (int l = 0; l < 64; l += 2) {
        float s0  = sc[l];
        float4 v0 = vrow[(long long)l * 256];
        acc0.x += s0 * v0.x; acc0.y += s0 * v0.y; acc0.z += s0 * v0.z; acc0.w += s0 * v0.w;
        float s1  = sc[l + 1];
        float4 v1 = vrow[(long long)(l + 1) * 256];
        acc1.x += s1 * v1.x; acc1.y += s1 * v1.y; acc1.z += s1 * v1.z; acc1.w += s1 * v1.w;
    }
    float* dst = vbar + b * HDIM + t * 4;
    atomicAdd(dst + 0, acc0.x + acc1.x);
    atomicAdd(dst + 1, acc0.y + acc1.y);
    atomicAdd(dst + 2, acc0.z + acc1.z);
    atomicAdd(dst + 3, acc0.w + acc1.w);
}

// result[b,o] = sum_h W[o,h] * vbar[b,h]. One wave per o; W row in registers.
__global__ __launch_bounds__(256, 4) void k_result(const float4* __restrict__ W4,
                                                   const float4* __restrict__ vbar4,
                                                   float* __restrict__ result) {
    int t = threadIdx.x;
    int lane = t & 63, wave = t >> 6;
    int o = blockIdx.x * 4 + wave;   // 256 blocks -> [0,1024)
    float4 w[4];
    #pragma unroll
    for (int i = 0; i < 4; ++i)
        w[i] = W4[o * 256 + lane + 64 * i];
    for (int b = 0; b < BDIM; b += 2) {
        float acc0 = 0.f, acc1 = 0.f;
        #pragma unroll
        for (int i = 0; i < 4; ++i) {
            float4 v0 = vbar4[b * 256 + lane + 64 * i];
            acc0 += v0.x * w[i].x + v0.y * w[i].y + v0.z * w[i].z + v0.w * w[i].w;
            float4 v1 = vbar4[(b + 1) * 256 + lane + 64 * i];
            acc1 += v1.x * w[i].x + v1.y * w[i].y + v1.z * w[i].z + v1.w * w[i].w;
        }
        #pragma unroll
        for (int off = 32; off > 0; off >>= 1) {
            acc0 += __shfl_down(acc0, off, 64);
            acc1 += __shfl_down(acc1, off, 64);
        }
        if (lane == 0) {
            result[b * HDIM + o]       = acc0;
            result[(b + 1) * HDIM + o] = acc1;
        }
    }
}

extern "C" void kernel_launch(void* const* d_in, const int* in_sizes, int n_in,
                              void* d_out, int out_size, void* d_ws, size_t ws_size,
                              hipStream_t stream) {
    const float* query = (const float*)d_in[0];
    const float* key   = (const float*)d_in[1];
    const float* value = (const float*)d_in[2];
    const float* W     = (const float*)d_in[3];
    const float* mlp_w = (const float*)d_in[4];
    const float* mlp_b = (const float*)d_in[5];

    float* out    = (float*)d_out;
    float* result = out;                 // B*H
    float* score  = out + BDIM * LDIM;   // B*L

    float* u1     = (float*)d_ws;
    float* u2     = u1 + HDIM;
    float* vbar   = u2 + HDIM;           // B*H
    float* logits = vbar + BDIM * HDIM;  // B*L

    hipMemsetAsync(d_ws, 0, (size_t)(2 * HDIM + BDIM * HDIM) * sizeof(float), stream);

    k_u12<<<64, 256, 0, stream>>>((const float4*)W, mlp_w, u1, u2);
    k_logits<<<2048, 256, 0, stream>>>((const float4*)query, (const float4*)key,
                                       (const float4*)u1, (const float4*)u2, mlp_b, logits);
    k_softmax<<<BDIM, 256, 0, stream>>>(logits, score);
    k_vbar<<<BDIM * 16, 256, 0, stream>>>((const float4*)value, score, vbar);
    k_result<<<256, 256, 0, stream>>>((const float4*)W, (const float4*)vbar, out);
}